// Round 4
// baseline (34.475 us; speedup 1.0000x reference)
//
#include <hip/hip_runtime.h>

// RankPool1d: window=16, stride=1, pad=8 (zeros), rank=8 (0-based 7),
// stable argsort tie-break. Outputs: values f32 [OUT_LEN], sel (as f32) [OUT_LEN].
//
// Per thread: 16 consecutive outputs via sliding rank maintenance (biased
// ranks R[j] = rank + window_idx; slide = two carry-adds per element).
// Outputs transposed through LDS (XOR-swizzled, all patterns <=2-way banked);
// sel staged as packed bytes (4/u32) -> LDS 20KB/block -> 5 blocks/CU with
// __launch_bounds__(256,5). Grid exactly 1024 blocks; the final output is
// folded into the last thread (window m=16 lives in its w[16..31]).

constexpr int L_IN    = 4194304;
constexpr int OUT_LEN = L_IN + 1;      // 4194305
constexpr int MOUT    = 16;            // outputs per thread
constexpr int TPB     = 256;
constexpr int OPB     = TPB * MOUT;    // 4096 outputs per block

// value LDS: element p stored at [(p&15)*256 + ((p>>4) ^ (2*(p&15)))]
__device__ __forceinline__ int lvidx(int p) {
    return (p & 15) * TPB + ((p >> 4) ^ (2 * (p & 15)));
}
// sel words: word q (outputs 4q..4q+3) at [(q&3)*256 + ((q>>2) ^ (8*(q&3)))]
__device__ __forceinline__ int lsidx(int q) {
    return (q & 3) * TPB + ((q >> 2) ^ (8 * (q & 3)));
}

__global__ __launch_bounds__(TPB, 5) void rankpool_kernel(const float* __restrict__ x,
                                                          float* __restrict__ dout) {
    __shared__ float    lv[MOUT * TPB];      // 16 KB values
    __shared__ unsigned ws32[4 * TPB];       // 4 KB packed sel bytes

    const int t   = threadIdx.x;
    const int blk = blockIdx.x;
    const int tid = blk * TPB + t;           // 0..262143
    const int o0  = tid * MOUT;
    const int base = o0 - 8;
    const bool extra = (tid == TPB * 1024 - 1);   // last thread also does output OUT_LEN-1

    // ---- load 32 inputs (windows m=0..15 need base..base+30) ----
    float w[32];
    if (base >= 0 && base + 32 <= L_IN) {
        const float4* p = reinterpret_cast<const float4*>(x + base); // 16B aligned
        #pragma unroll
        for (int q = 0; q < 8; ++q) {
            float4 v = p[q];
            w[4*q+0] = v.x; w[4*q+1] = v.y; w[4*q+2] = v.z; w[4*q+3] = v.w;
        }
    } else {
        #pragma unroll
        for (int i = 0; i < 32; ++i) {
            int g = base + i;
            w[i] = (g >= 0 && g < L_IN) ? x[g] : 0.0f;   // PAD_VALUE = 0
        }
    }

    // ---- biased ranks for window 0 (R[j] = stable rank; init R[j]=j) ----
    int R[32];
    #pragma unroll
    for (int j = 0; j < 16; ++j) R[j] = j;
    #pragma unroll
    for (int j = 0; j < 16; ++j) {
        #pragma unroll
        for (int k = j + 1; k < 16; ++k) {
            int c = (w[k] < w[j]);
            R[j] += c;
            R[k] -= c;
        }
    }

    // ---- per-window select + slide ----
    unsigned pk[4] = {0u, 0u, 0u, 0u};       // packed sel bytes
    #pragma unroll
    for (int m = 0; m < MOUT; ++m) {
        int   sel = 0;
        float val = w[m];
        #pragma unroll
        for (int j = m; j < m + 16; ++j) {
            bool c = (R[j] == 7 + m);
            sel = c ? (j - m) : sel;
            val = c ? w[j]    : val;
        }
        lv[lvidx(t * MOUT + m)] = val;
        pk[m >> 2] |= ((unsigned)sel) << (8 * (m & 3));

        if (m < MOUT - 1) {
            const float wm = w[m];           // departing (oldest)
            const float wn = w[m + 16];      // entering (newest)
            int s = 0;
            #pragma unroll
            for (int j = m + 1; j < m + 16; ++j) {
                R[j] += (int)(w[j] < wm);
                int c2 = (wn < w[j]);
                R[j] += c2;
                s    += c2;
            }
            R[m + 16] = 16 + m - s;          // (15-s) + (m+1) bias
        }
    }
    #pragma unroll
    for (int a = 0; a < 4; ++a)
        ws32[lsidx(t * 4 + a)] = pk[a];

    // ---- final output (window m=16 of the very last thread) ----
    if (extra) {
        const float wm = w[15], wn = w[31];
        int s = 0;
        #pragma unroll
        for (int j = 16; j < 31; ++j) {
            R[j] += (int)(w[j] < wm);
            int c2 = (wn < w[j]);
            R[j] += c2;
            s    += c2;
        }
        R[31] = 31 - s;
        int sel = 0; float val = w[16];
        #pragma unroll
        for (int j = 16; j < 32; ++j) {
            bool c = (R[j] == 23);           // 7 + 16
            sel = c ? (j - 16) : sel;
            val = c ? w[j]     : val;
        }
        dout[OUT_LEN - 1]     = val;
        dout[2 * OUT_LEN - 1] = (float)sel;
    }

    __syncthreads();

    // ---- cooperative float4 global stores ----
    const int blockStart = blk * OPB;

    // values: aligned float4
    #pragma unroll
    for (int k = 0; k < 4; ++k) {
        int p = 4 * (t + TPB * k);
        float4 v;
        v.x = lv[lvidx(p + 0)];
        v.y = lv[lvidx(p + 1)];
        v.z = lv[lvidx(p + 2)];
        v.w = lv[lvidx(p + 3)];
        *reinterpret_cast<float4*>(dout + blockStart + p) = v;
    }

    // sel: global base (OUT_LEN + blockStart) == 1 mod 4 -> +3 shift aligns
    float* s0 = dout + OUT_LEN + blockStart;
    if (t < 3) {
        unsigned w0 = ws32[lsidx(0)];
        s0[t] = (float)((w0 >> (8 * t)) & 0xffu);
    }
    if (t == 3) {
        unsigned wl = ws32[lsidx(1023)];
        s0[OPB - 1] = (float)(wl >> 24);
    }
    #pragma unroll
    for (int k = 0; k < 4; ++k) {
        int q = t + TPB * k;                 // chunk: outputs 4q+3 .. 4q+6
        if (q < 1023) {
            unsigned wa = ws32[lsidx(q)];
            unsigned wb = ws32[lsidx(q + 1)];
            float4 v;
            v.x = (float)(wa >> 24);                 // output 4q+3
            v.y = (float)( wb        & 0xffu);       // 4q+4
            v.z = (float)((wb >>  8) & 0xffu);       // 4q+5
            v.w = (float)((wb >> 16) & 0xffu);       // 4q+6
            *reinterpret_cast<float4*>(s0 + 3 + 4 * q) = v;   // 16B aligned
        }
    }
}

extern "C" void kernel_launch(void* const* d_in, const int* in_sizes, int n_in,
                              void* d_out, int out_size, void* d_ws, size_t ws_size,
                              hipStream_t stream) {
    const float* x = (const float*)d_in[0];
    float* out = (float*)d_out;
    rankpool_kernel<<<1024, TPB, 0, stream>>>(x, out);
}

// Round 5
// 29.396 us; speedup vs baseline: 1.1728x; 1.1728x over previous
//
#include <hip/hip_runtime.h>

// RankPool1d: window=16, stride=1, pad=8 (zeros), rank=8 (0-based 7),
// stable argsort tie-break. Outputs: values f32 [OUT_LEN], sel (as f32) [OUT_LEN].
//
// Per thread: 16 consecutive outputs via sliding rank maintenance (biased
// ranks R[j] = rank + window_idx; slide = two carry-adds per element).
// Outputs transposed through LDS (XOR-swizzled, all patterns <=2-way banked);
// sel staged as packed bytes (4/u32) -> LDS 20KB/block. Grid exactly 1024
// blocks; final output folded into the last thread.
//
// __launch_bounds__(256,4): VGPR cap 128. (256,5) forced cap ~96 -> compiler
// spilled w[32]/R[32] to scratch: VGPR_Count=48, WRITE_SIZE 79MB, VALUBusy
// 0.8%, dur 34us. Do NOT raise the min-waves arg on this kernel.

constexpr int L_IN    = 4194304;
constexpr int OUT_LEN = L_IN + 1;      // 4194305
constexpr int MOUT    = 16;            // outputs per thread
constexpr int TPB     = 256;
constexpr int OPB     = TPB * MOUT;    // 4096 outputs per block

// value LDS: element p stored at [(p&15)*256 + ((p>>4) ^ (2*(p&15)))]
__device__ __forceinline__ int lvidx(int p) {
    return (p & 15) * TPB + ((p >> 4) ^ (2 * (p & 15)));
}
// sel words: word q (outputs 4q..4q+3) at [(q&3)*256 + ((q>>2) ^ (8*(q&3)))]
__device__ __forceinline__ int lsidx(int q) {
    return (q & 3) * TPB + ((q >> 2) ^ (8 * (q & 3)));
}

__global__ __launch_bounds__(TPB, 4) void rankpool_kernel(const float* __restrict__ x,
                                                          float* __restrict__ dout) {
    __shared__ float    lv[MOUT * TPB];      // 16 KB values
    __shared__ unsigned ws32[4 * TPB];       // 4 KB packed sel bytes

    const int t   = threadIdx.x;
    const int blk = blockIdx.x;
    const int tid = blk * TPB + t;           // 0..262143
    const int o0  = tid * MOUT;
    const int base = o0 - 8;
    const bool extra = (tid == TPB * 1024 - 1);   // last thread also does output OUT_LEN-1

    // ---- load 32 inputs (windows m=0..15 need base..base+30) ----
    float w[32];
    if (base >= 0 && base + 32 <= L_IN) {
        const float4* p = reinterpret_cast<const float4*>(x + base); // 16B aligned
        #pragma unroll
        for (int q = 0; q < 8; ++q) {
            float4 v = p[q];
            w[4*q+0] = v.x; w[4*q+1] = v.y; w[4*q+2] = v.z; w[4*q+3] = v.w;
        }
    } else {
        #pragma unroll
        for (int i = 0; i < 32; ++i) {
            int g = base + i;
            w[i] = (g >= 0 && g < L_IN) ? x[g] : 0.0f;   // PAD_VALUE = 0
        }
    }

    // ---- biased ranks for window 0 (R[j] = stable rank; init R[j]=j) ----
    int R[32];
    #pragma unroll
    for (int j = 0; j < 16; ++j) R[j] = j;
    #pragma unroll
    for (int j = 0; j < 16; ++j) {
        #pragma unroll
        for (int k = j + 1; k < 16; ++k) {
            int c = (w[k] < w[j]);
            R[j] += c;
            R[k] -= c;
        }
    }

    // ---- per-window select + slide ----
    unsigned pk[4] = {0u, 0u, 0u, 0u};       // packed sel bytes
    #pragma unroll
    for (int m = 0; m < MOUT; ++m) {
        int   sel = 0;
        float val = w[m];
        #pragma unroll
        for (int j = m; j < m + 16; ++j) {
            bool c = (R[j] == 7 + m);
            sel = c ? (j - m) : sel;
            val = c ? w[j]    : val;
        }
        lv[lvidx(t * MOUT + m)] = val;
        pk[m >> 2] |= ((unsigned)sel) << (8 * (m & 3));

        if (m < MOUT - 1) {
            const float wm = w[m];           // departing (oldest)
            const float wn = w[m + 16];      // entering (newest)
            int s = 0;
            #pragma unroll
            for (int j = m + 1; j < m + 16; ++j) {
                R[j] += (int)(w[j] < wm);
                int c2 = (wn < w[j]);
                R[j] += c2;
                s    += c2;
            }
            R[m + 16] = 16 + m - s;          // (15-s) + (m+1) bias
        }
    }
    #pragma unroll
    for (int a = 0; a < 4; ++a)
        ws32[lsidx(t * 4 + a)] = pk[a];

    // ---- final output (window m=16 of the very last thread) ----
    if (extra) {
        const float wm = w[15], wn = w[31];
        int s = 0;
        #pragma unroll
        for (int j = 16; j < 31; ++j) {
            R[j] += (int)(w[j] < wm);
            int c2 = (wn < w[j]);
            R[j] += c2;
            s    += c2;
        }
        R[31] = 31 - s;
        int sel = 0; float val = w[16];
        #pragma unroll
        for (int j = 16; j < 32; ++j) {
            bool c = (R[j] == 23);           // 7 + 16
            sel = c ? (j - 16) : sel;
            val = c ? w[j]     : val;
        }
        dout[OUT_LEN - 1]     = val;
        dout[2 * OUT_LEN - 1] = (float)sel;
    }

    __syncthreads();

    // ---- cooperative float4 global stores ----
    const int blockStart = blk * OPB;

    // values: aligned float4
    #pragma unroll
    for (int k = 0; k < 4; ++k) {
        int p = 4 * (t + TPB * k);
        float4 v;
        v.x = lv[lvidx(p + 0)];
        v.y = lv[lvidx(p + 1)];
        v.z = lv[lvidx(p + 2)];
        v.w = lv[lvidx(p + 3)];
        *reinterpret_cast<float4*>(dout + blockStart + p) = v;
    }

    // sel: global base (OUT_LEN + blockStart) == 1 mod 4 -> +3 shift aligns
    float* s0 = dout + OUT_LEN + blockStart;
    if (t < 3) {
        unsigned w0 = ws32[lsidx(0)];
        s0[t] = (float)((w0 >> (8 * t)) & 0xffu);
    }
    if (t == 3) {
        unsigned wl = ws32[lsidx(1023)];
        s0[OPB - 1] = (float)(wl >> 24);
    }
    #pragma unroll
    for (int k = 0; k < 4; ++k) {
        int q = t + TPB * k;                 // chunk: outputs 4q+3 .. 4q+6
        if (q < 1023) {
            unsigned wa = ws32[lsidx(q)];
            unsigned wb = ws32[lsidx(q + 1)];
            float4 v;
            v.x = (float)(wa >> 24);                 // output 4q+3
            v.y = (float)( wb        & 0xffu);       // 4q+4
            v.z = (float)((wb >>  8) & 0xffu);       // 4q+5
            v.w = (float)((wb >> 16) & 0xffu);       // 4q+6
            *reinterpret_cast<float4*>(s0 + 3 + 4 * q) = v;   // 16B aligned
        }
    }
}

extern "C" void kernel_launch(void* const* d_in, const int* in_sizes, int n_in,
                              void* d_out, int out_size, void* d_ws, size_t ws_size,
                              hipStream_t stream) {
    const float* x = (const float*)d_in[0];
    float* out = (float*)d_out;
    rankpool_kernel<<<1024, TPB, 0, stream>>>(x, out);
}

// Round 6
// 24.184 us; speedup vs baseline: 1.4256x; 1.2155x over previous
//
#include <hip/hip_runtime.h>

// RankPool1d: window=16, stride=1, pad=8 (zeros), rank=8 (0-based 7),
// stable argsort tie-break. Outputs: values f32 [OUT_LEN], sel (as f32) [OUT_LEN].
//
// Per thread: 16 consecutive outputs via sliding rank maintenance (biased
// ranks R[j] = rank + window_idx; slide = two carry-adds per element).
// Outputs transposed through LDS (XOR-swizzled, all patterns <=2-way banked);
// sel staged as packed bytes (4/u32) -> LDS 20KB/block. Grid exactly 1024
// blocks; final output folded into the last thread.
//
// LAUNCH BOUNDS: bare (256) ONLY. Any min-waves second arg makes hipcc spill
// the w[32]/R[32] working set to scratch:
//   (256,5) -> VGPR 48, WRITE 79MB, 34.5us;  (256,4) -> VGPR 64, occ 1%, 29.4us
//   (256)   -> no spill (R3: 23.4us). Do not add a second argument.

constexpr int L_IN    = 4194304;
constexpr int OUT_LEN = L_IN + 1;      // 4194305
constexpr int MOUT    = 16;            // outputs per thread
constexpr int TPB     = 256;
constexpr int OPB     = TPB * MOUT;    // 4096 outputs per block

// value LDS: element p stored at [(p&15)*256 + ((p>>4) ^ (2*(p&15)))]
__device__ __forceinline__ int lvidx(int p) {
    return (p & 15) * TPB + ((p >> 4) ^ (2 * (p & 15)));
}
// sel words: word q (outputs 4q..4q+3) at [(q&3)*256 + ((q>>2) ^ (8*(q&3)))]
__device__ __forceinline__ int lsidx(int q) {
    return (q & 3) * TPB + ((q >> 2) ^ (8 * (q & 3)));
}

__global__ __launch_bounds__(TPB) void rankpool_kernel(const float* __restrict__ x,
                                                       float* __restrict__ dout) {
    __shared__ float    lv[MOUT * TPB];      // 16 KB values
    __shared__ unsigned ws32[4 * TPB];       // 4 KB packed sel bytes

    const int t   = threadIdx.x;
    const int blk = blockIdx.x;
    const int tid = blk * TPB + t;           // 0..262143
    const int o0  = tid * MOUT;
    const int base = o0 - 8;
    const bool extra = (tid == TPB * 1024 - 1);   // last thread also does output OUT_LEN-1

    // ---- load 32 inputs (windows m=0..15 need base..base+30) ----
    float w[32];
    if (base >= 0 && base + 32 <= L_IN) {
        const float4* p = reinterpret_cast<const float4*>(x + base); // 16B aligned
        #pragma unroll
        for (int q = 0; q < 8; ++q) {
            float4 v = p[q];
            w[4*q+0] = v.x; w[4*q+1] = v.y; w[4*q+2] = v.z; w[4*q+3] = v.w;
        }
    } else {
        #pragma unroll
        for (int i = 0; i < 32; ++i) {
            int g = base + i;
            w[i] = (g >= 0 && g < L_IN) ? x[g] : 0.0f;   // PAD_VALUE = 0
        }
    }

    // ---- biased ranks for window 0 (R[j] = stable rank; init R[j]=j) ----
    int R[32];
    #pragma unroll
    for (int j = 0; j < 16; ++j) R[j] = j;
    #pragma unroll
    for (int j = 0; j < 16; ++j) {
        #pragma unroll
        for (int k = j + 1; k < 16; ++k) {
            int c = (w[k] < w[j]);
            R[j] += c;
            R[k] -= c;
        }
    }

    // ---- per-window select + slide ----
    unsigned pk[4] = {0u, 0u, 0u, 0u};       // packed sel bytes
    #pragma unroll
    for (int m = 0; m < MOUT; ++m) {
        int   sel = 0;
        float val = w[m];
        #pragma unroll
        for (int j = m; j < m + 16; ++j) {
            bool c = (R[j] == 7 + m);
            sel = c ? (j - m) : sel;
            val = c ? w[j]    : val;
        }
        lv[lvidx(t * MOUT + m)] = val;
        pk[m >> 2] |= ((unsigned)sel) << (8 * (m & 3));

        if (m < MOUT - 1) {
            const float wm = w[m];           // departing (oldest)
            const float wn = w[m + 16];      // entering (newest)
            int s = 0;
            #pragma unroll
            for (int j = m + 1; j < m + 16; ++j) {
                R[j] += (int)(w[j] < wm);
                int c2 = (wn < w[j]);
                R[j] += c2;
                s    += c2;
            }
            R[m + 16] = 16 + m - s;          // (15-s) + (m+1) bias
        }
    }
    #pragma unroll
    for (int a = 0; a < 4; ++a)
        ws32[lsidx(t * 4 + a)] = pk[a];

    // ---- final output (window m=16 of the very last thread) ----
    if (extra) {
        const float wm = w[15], wn = w[31];
        int s = 0;
        #pragma unroll
        for (int j = 16; j < 31; ++j) {
            R[j] += (int)(w[j] < wm);
            int c2 = (wn < w[j]);
            R[j] += c2;
            s    += c2;
        }
        R[31] = 31 - s;
        int sel = 0; float val = w[16];
        #pragma unroll
        for (int j = 16; j < 32; ++j) {
            bool c = (R[j] == 23);           // 7 + 16
            sel = c ? (j - 16) : sel;
            val = c ? w[j]     : val;
        }
        dout[OUT_LEN - 1]     = val;
        dout[2 * OUT_LEN - 1] = (float)sel;
    }

    __syncthreads();

    // ---- cooperative float4 global stores ----
    const int blockStart = blk * OPB;

    // values: aligned float4
    #pragma unroll
    for (int k = 0; k < 4; ++k) {
        int p = 4 * (t + TPB * k);
        float4 v;
        v.x = lv[lvidx(p + 0)];
        v.y = lv[lvidx(p + 1)];
        v.z = lv[lvidx(p + 2)];
        v.w = lv[lvidx(p + 3)];
        *reinterpret_cast<float4*>(dout + blockStart + p) = v;
    }

    // sel: global base (OUT_LEN + blockStart) == 1 mod 4 -> +3 shift aligns
    float* s0 = dout + OUT_LEN + blockStart;
    if (t < 3) {
        unsigned w0 = ws32[lsidx(0)];
        s0[t] = (float)((w0 >> (8 * t)) & 0xffu);
    }
    if (t == 3) {
        unsigned wl = ws32[lsidx(1023)];
        s0[OPB - 1] = (float)(wl >> 24);
    }
    #pragma unroll
    for (int k = 0; k < 4; ++k) {
        int q = t + TPB * k;                 // chunk: outputs 4q+3 .. 4q+6
        if (q < 1023) {
            unsigned wa = ws32[lsidx(q)];
            unsigned wb = ws32[lsidx(q + 1)];
            float4 v;
            v.x = (float)(wa >> 24);                 // output 4q+3
            v.y = (float)( wb        & 0xffu);       // 4q+4
            v.z = (float)((wb >>  8) & 0xffu);       // 4q+5
            v.w = (float)((wb >> 16) & 0xffu);       // 4q+6
            *reinterpret_cast<float4*>(s0 + 3 + 4 * q) = v;   // 16B aligned
        }
    }
}

extern "C" void kernel_launch(void* const* d_in, const int* in_sizes, int n_in,
                              void* d_out, int out_size, void* d_ws, size_t ws_size,
                              hipStream_t stream) {
    const float* x = (const float*)d_in[0];
    float* out = (float*)d_out;
    rankpool_kernel<<<1024, TPB, 0, stream>>>(x, out);
}